// Round 1
// baseline (2861.337 us; speedup 1.0000x reference)
//
#include <hip/hip_runtime.h>
#include <hip/hip_bf16.h>

#define N_NODES 50000
#define IN_DIM 256
#define OUT_DIM 128
#define ODIM2 256        // mu(128) + logstd(128) concatenated
#define NEDGE 800000
#define MAX_LOGSTD 10.0f

__device__ __forceinline__ float b2f(unsigned short u) {
    union { unsigned int i; float f; } v; v.i = ((unsigned int)u) << 16; return v.f;
}
__device__ __forceinline__ unsigned short f2b(float f) {
    union { float f; unsigned int i; } v; v.f = f;
    unsigned int x = v.i;
    unsigned int r = (x + 0x7fffu + ((x >> 16) & 1u)) >> 16;
    return (unsigned short)r;
}

// Normalize edge_index to int32 in ws. Detect int64 (harness may deliver either):
// as int32 words, int64 values < 2^31 appear as (lo, 0) pairs -> odd words all zero.
__global__ void k_edges(const int* __restrict__ raw, int* __restrict__ ei32) {
    bool is64 = true;
    #pragma unroll
    for (int i = 0; i < 8; i++) if (raw[2 * i + 1] != 0) is64 = false;
    int idx = blockIdx.x * blockDim.x + threadIdx.x;
    if (idx < 2 * NEDGE) ei32[idx] = is64 ? raw[2 * idx] : raw[idx];
}

__global__ void k_degree(const int* __restrict__ ei, float* __restrict__ deg) {
    int e = blockIdx.x * blockDim.x + threadIdx.x;
    if (e < NEDGE) atomicAdd(&deg[ei[NEDGE + e]], 1.0f);
}

__global__ void k_dinv(float* __restrict__ deg) {
    int n = blockIdx.x * blockDim.x + threadIdx.x;
    if (n < N_NODES) deg[n] = rsqrtf(deg[n] + 1.0f);
}

// Fused GEMM: h[n, 0:128] = x[n,:]@W_mu ; h[n,128:256] = x[n,:]@W_logstd (bf16)
// Also init agg[n,c] = h[n,c] * dinv[n]^2  (self-loop term, f32).
// Block: 256 threads, 16 rows. Thread = (col 0..63, rowgroup 0..3), 4x4 microtile.
__global__ __launch_bounds__(256) void k_gemm(
    const float* __restrict__ x, const float* __restrict__ Wmu,
    const float* __restrict__ Wls, const float* __restrict__ dinv,
    unsigned short* __restrict__ h, float* __restrict__ agg)
{
    __shared__ float xs[16][IN_DIM];   // 16 KB
    const int tid  = threadIdx.x;
    const int row0 = blockIdx.x * 16;

    // stage x tile: 1024 float4, 4 per thread, coalesced
    const float4* xv  = (const float4*)(x + (size_t)row0 * IN_DIM);
    float4* xsv = (float4*)(&xs[0][0]);
    #pragma unroll
    for (int i = 0; i < 4; i++) xsv[tid + i * 256] = xv[tid + i * 256];
    __syncthreads();

    const int col = tid & 63;
    const int rg  = tid >> 6;   // 0..3 -> rows rg*4 .. rg*4+3

    float acc[4][4];
    #pragma unroll
    for (int i = 0; i < 4; i++)
        #pragma unroll
        for (int j = 0; j < 4; j++) acc[i][j] = 0.0f;

    const float* wm0 = Wmu + col;
    const float* wm1 = Wmu + col + 64;
    const float* wl0 = Wls + col;
    const float* wl1 = Wls + col + 64;

    #pragma unroll 4
    for (int k = 0; k < IN_DIM; k++) {
        float w0 = wm0[k * OUT_DIM];
        float w1 = wm1[k * OUT_DIM];
        float w2 = wl0[k * OUT_DIM];
        float w3 = wl1[k * OUT_DIM];
        #pragma unroll
        for (int i = 0; i < 4; i++) {
            float xr = xs[rg * 4 + i][k];
            acc[i][0] = fmaf(xr, w0, acc[i][0]);
            acc[i][1] = fmaf(xr, w1, acc[i][1]);
            acc[i][2] = fmaf(xr, w2, acc[i][2]);
            acc[i][3] = fmaf(xr, w3, acc[i][3]);
        }
    }

    #pragma unroll
    for (int i = 0; i < 4; i++) {
        int row = row0 + rg * 4 + i;
        float dv = dinv[row];
        float d2 = dv * dv;
        size_t base = (size_t)row * ODIM2;
        #pragma unroll
        for (int j = 0; j < 4; j++) {
            int c = col + j * 64;   // 0:mu, 64:mu, 128:ls, 192:ls
            float v = acc[i][j];
            h[base + c]   = f2b(v);
            agg[base + c] = v * d2;
        }
    }
}

// One wave per edge: gather h[src] (bf16x4/lane), scale by coef, atomicAdd into agg[dst].
__global__ __launch_bounds__(256) void k_scatter(
    const int* __restrict__ ei, const float* __restrict__ dinv,
    const unsigned short* __restrict__ h, float* __restrict__ agg)
{
    int tid  = threadIdx.x;
    int e    = blockIdx.x * 4 + (tid >> 6);
    int lane = tid & 63;
    if (e >= NEDGE) return;
    int src = ei[e];
    int dst = ei[NEDGE + e];
    float coef = dinv[src] * dinv[dst];
    const ushort4* hp = (const ushort4*)(h + (size_t)src * ODIM2);
    ushort4 v = hp[lane];
    float* ap = agg + (size_t)dst * ODIM2 + lane * 4;
    atomicAdd(ap + 0, coef * b2f(v.x));
    atomicAdd(ap + 1, coef * b2f(v.y));
    atomicAdd(ap + 2, coef * b2f(v.z));
    atomicAdd(ap + 3, coef * b2f(v.w));
}

// z = (agg_mu + b_mu) + eps * exp(min(agg_ls + b_ls, 10))
__global__ void k_final(const float* __restrict__ agg, const float* __restrict__ bmu,
                        const float* __restrict__ bls, const float* __restrict__ eps,
                        float* __restrict__ z)
{
    int gid = blockIdx.x * blockDim.x + threadIdx.x;  // one thread = 4 outputs
    const int total = N_NODES * OUT_DIM / 4;
    if (gid >= total) return;
    int n  = gid >> 5;            // 32 groups of 4 per row
    int c4 = (gid & 31) * 4;
    float4 mu = *(const float4*)(agg + (size_t)n * ODIM2 + c4);
    float4 ls = *(const float4*)(agg + (size_t)n * ODIM2 + 128 + c4);
    float4 ep = *(const float4*)(eps + (size_t)n * OUT_DIM + c4);
    float4 bm = *(const float4*)(bmu + c4);
    float4 bl = *(const float4*)(bls + c4);
    float4 o;
    o.x = mu.x + bm.x + ep.x * expf(fminf(ls.x + bl.x, MAX_LOGSTD));
    o.y = mu.y + bm.y + ep.y * expf(fminf(ls.y + bl.y, MAX_LOGSTD));
    o.z = mu.z + bm.z + ep.z * expf(fminf(ls.z + bl.z, MAX_LOGSTD));
    o.w = mu.w + bm.w + ep.w * expf(fminf(ls.w + bl.w, MAX_LOGSTD));
    *(float4*)(z + (size_t)n * OUT_DIM + c4) = o;
}

extern "C" void kernel_launch(void* const* d_in, const int* in_sizes, int n_in,
                              void* d_out, int out_size, void* d_ws, size_t ws_size,
                              hipStream_t stream) {
    const float* x   = (const float*)d_in[0];
    const int*   ei  = (const int*)  d_in[1];
    const float* Wmu = (const float*)d_in[2];
    const float* bmu = (const float*)d_in[3];
    const float* Wls = (const float*)d_in[4];
    const float* bls = (const float*)d_in[5];
    const float* eps = (const float*)d_in[6];
    float* z = (float*)d_out;

    char* ws = (char*)d_ws;
    size_t off = 0;
    float* deg = (float*)(ws + off);                       // N f32 (becomes dinv)
    off += ((size_t)N_NODES * 4 + 255) & ~(size_t)255;
    int* ei32 = (int*)(ws + off);                          // 2E i32
    off += ((size_t)2 * NEDGE * 4 + 255) & ~(size_t)255;
    unsigned short* h = (unsigned short*)(ws + off);       // N*256 bf16
    off += ((size_t)N_NODES * ODIM2 * 2 + 255) & ~(size_t)255;
    float* agg = (float*)(ws + off);                       // N*256 f32
    off += (size_t)N_NODES * ODIM2 * 4;

    hipMemsetAsync(deg, 0, N_NODES * sizeof(float), stream);

    k_edges  <<<(2 * NEDGE + 255) / 256, 256, 0, stream>>>(ei, ei32);
    k_degree <<<(NEDGE + 255) / 256,      256, 0, stream>>>(ei32, deg);
    k_dinv   <<<(N_NODES + 255) / 256,    256, 0, stream>>>(deg);
    k_gemm   <<<N_NODES / 16,             256, 0, stream>>>(x, Wmu, Wls, deg, h, agg);
    k_scatter<<<(NEDGE + 3) / 4,          256, 0, stream>>>(ei32, deg, h, agg);
    k_final  <<<(N_NODES * OUT_DIM / 4 + 255) / 256, 256, 0, stream>>>(agg, bmu, bls, eps, z);
}

// Round 2
// 396.223 us; speedup vs baseline: 7.2215x; 7.2215x over previous
//
#include <hip/hip_runtime.h>
#include <hip/hip_bf16.h>

#define N_NODES 50000
#define IN_DIM 256
#define OUT_DIM 128
#define ODIM2 256        // mu(128) + logstd(128) concatenated
#define NEDGE 800000
#define MAX_LOGSTD 10.0f
#define SCAN_THREADS 1024
#define SCAN_CHUNK 49    // 1024*49 = 50176 >= 50000

__device__ __forceinline__ float b2f(unsigned short u) {
    union { unsigned int i; float f; } v; v.i = ((unsigned int)u) << 16; return v.f;
}
__device__ __forceinline__ unsigned short f2b(float f) {
    union { float f; unsigned int i; } v; v.f = f;
    unsigned int x = v.i;
    unsigned int r = (x + 0x7fffu + ((x >> 16) & 1u)) >> 16;
    return (unsigned short)r;
}

// Normalize edge_index to int32 in ws. Detect int64 (harness may deliver either):
// as int32 words, int64 values < 2^31 appear as (lo, 0) pairs -> odd words all zero.
__global__ void k_edges(const int* __restrict__ raw, int* __restrict__ ei32) {
    bool is64 = true;
    #pragma unroll
    for (int i = 0; i < 8; i++) if (raw[2 * i + 1] != 0) is64 = false;
    int idx = blockIdx.x * blockDim.x + threadIdx.x;
    if (idx < 2 * NEDGE) ei32[idx] = is64 ? raw[2 * idx] : raw[idx];
}

// Histogram of dst -> cnt[]
__global__ void k_count(const int* __restrict__ ei, int* __restrict__ cnt) {
    int e = blockIdx.x * blockDim.x + threadIdx.x;
    if (e < NEDGE) atomicAdd(&cnt[ei[NEDGE + e]], 1);
}

__global__ void k_dinv(const int* __restrict__ cnt, float* __restrict__ dinv) {
    int n = blockIdx.x * blockDim.x + threadIdx.x;
    if (n < N_NODES) dinv[n] = rsqrtf((float)cnt[n] + 1.0f);
}

// Single-block exclusive scan: row_start[N+1], pos[] = copy of row_start[0..N-1]
__global__ __launch_bounds__(SCAN_THREADS) void k_scan(
    const int* __restrict__ cnt, int* __restrict__ row_start, int* __restrict__ pos)
{
    __shared__ int part[SCAN_THREADS];
    int t = threadIdx.x;
    int base = t * SCAN_CHUNK;
    int s = 0;
    for (int i = 0; i < SCAN_CHUNK; i++) {
        int idx = base + i;
        if (idx < N_NODES) s += cnt[idx];
    }
    part[t] = s;
    __syncthreads();
    // Hillis-Steele inclusive scan over 1024 partials
    for (int off = 1; off < SCAN_THREADS; off <<= 1) {
        int v = (t >= off) ? part[t - off] : 0;
        __syncthreads();
        part[t] += v;
        __syncthreads();
    }
    int run = (t == 0) ? 0 : part[t - 1];
    for (int i = 0; i < SCAN_CHUNK; i++) {
        int idx = base + i;
        if (idx < N_NODES) {
            row_start[idx] = run;
            pos[idx] = run;
            run += cnt[idx];
        }
    }
    if (t == SCAN_THREADS - 1) row_start[N_NODES] = run;
}

// Bin edges by dst: csr_src[row_start[dst] + k] = src
__global__ void k_fill(const int* __restrict__ ei, int* __restrict__ pos,
                       int* __restrict__ csr) {
    int e = blockIdx.x * blockDim.x + threadIdx.x;
    if (e < NEDGE) {
        int dst = ei[NEDGE + e];
        int p = atomicAdd(&pos[dst], 1);
        csr[p] = ei[e];
    }
}

// Fused GEMM: h[n, 0:128] = x[n,:]@W_mu ; h[n,128:256] = x[n,:]@W_logstd (bf16)
__global__ __launch_bounds__(256) void k_gemm(
    const float* __restrict__ x, const float* __restrict__ Wmu,
    const float* __restrict__ Wls, unsigned short* __restrict__ h)
{
    __shared__ float xs[16][IN_DIM];   // 16 KB
    const int tid  = threadIdx.x;
    const int row0 = blockIdx.x * 16;

    const float4* xv  = (const float4*)(x + (size_t)row0 * IN_DIM);
    float4* xsv = (float4*)(&xs[0][0]);
    #pragma unroll
    for (int i = 0; i < 4; i++) xsv[tid + i * 256] = xv[tid + i * 256];
    __syncthreads();

    const int col = tid & 63;
    const int rg  = tid >> 6;   // 0..3 -> rows rg*4 .. rg*4+3

    float acc[4][4];
    #pragma unroll
    for (int i = 0; i < 4; i++)
        #pragma unroll
        for (int j = 0; j < 4; j++) acc[i][j] = 0.0f;

    const float* wm0 = Wmu + col;
    const float* wm1 = Wmu + col + 64;
    const float* wl0 = Wls + col;
    const float* wl1 = Wls + col + 64;

    #pragma unroll 4
    for (int k = 0; k < IN_DIM; k++) {
        float w0 = wm0[k * OUT_DIM];
        float w1 = wm1[k * OUT_DIM];
        float w2 = wl0[k * OUT_DIM];
        float w3 = wl1[k * OUT_DIM];
        #pragma unroll
        for (int i = 0; i < 4; i++) {
            float xr = xs[rg * 4 + i][k];
            acc[i][0] = fmaf(xr, w0, acc[i][0]);
            acc[i][1] = fmaf(xr, w1, acc[i][1]);
            acc[i][2] = fmaf(xr, w2, acc[i][2]);
            acc[i][3] = fmaf(xr, w3, acc[i][3]);
        }
    }

    #pragma unroll
    for (int i = 0; i < 4; i++) {
        int row = row0 + rg * 4 + i;
        size_t base = (size_t)row * ODIM2;
        #pragma unroll
        for (int j = 0; j < 4; j++) {
            int c = col + j * 64;   // 0:mu, 64:mu, 128:ls, 192:ls
            h[base + c] = f2b(acc[i][j]);
        }
    }
}

// One wave per dst node: pull all in-edges, fused self-loop + bias + reparam.
// Lane l holds h-cols l*4..l*4+3 (l<32: mu, l>=32: logstd).
__global__ __launch_bounds__(256) void k_gather(
    const int* __restrict__ row_start, const int* __restrict__ csr,
    const float* __restrict__ dinv, const unsigned short* __restrict__ h,
    const float* __restrict__ eps, const float* __restrict__ bmu,
    const float* __restrict__ bls, float* __restrict__ z)
{
    int tid  = threadIdx.x;
    int n    = blockIdx.x * 4 + (tid >> 6);
    int lane = tid & 63;
    float dn = dinv[n];

    float a0, a1, a2, a3;
    {   // self-loop: dinv^2 * h[n]
        ushort4 v = ((const ushort4*)(h + (size_t)n * ODIM2))[lane];
        float c = dn * dn;
        a0 = c * b2f(v.x); a1 = c * b2f(v.y); a2 = c * b2f(v.z); a3 = c * b2f(v.w);
    }

    int j   = row_start[n];
    int end = row_start[n + 1];
    for (; j + 4 <= end; j += 4) {
        int s0 = csr[j], s1 = csr[j + 1], s2 = csr[j + 2], s3 = csr[j + 3];
        float c0 = dinv[s0] * dn, c1 = dinv[s1] * dn;
        float c2 = dinv[s2] * dn, c3 = dinv[s3] * dn;
        ushort4 v0 = ((const ushort4*)(h + (size_t)s0 * ODIM2))[lane];
        ushort4 v1 = ((const ushort4*)(h + (size_t)s1 * ODIM2))[lane];
        ushort4 v2 = ((const ushort4*)(h + (size_t)s2 * ODIM2))[lane];
        ushort4 v3 = ((const ushort4*)(h + (size_t)s3 * ODIM2))[lane];
        a0 = fmaf(c0, b2f(v0.x), a0); a1 = fmaf(c0, b2f(v0.y), a1);
        a2 = fmaf(c0, b2f(v0.z), a2); a3 = fmaf(c0, b2f(v0.w), a3);
        a0 = fmaf(c1, b2f(v1.x), a0); a1 = fmaf(c1, b2f(v1.y), a1);
        a2 = fmaf(c1, b2f(v1.z), a2); a3 = fmaf(c1, b2f(v1.w), a3);
        a0 = fmaf(c2, b2f(v2.x), a0); a1 = fmaf(c2, b2f(v2.y), a1);
        a2 = fmaf(c2, b2f(v2.z), a2); a3 = fmaf(c2, b2f(v2.w), a3);
        a0 = fmaf(c3, b2f(v3.x), a0); a1 = fmaf(c3, b2f(v3.y), a1);
        a2 = fmaf(c3, b2f(v3.z), a2); a3 = fmaf(c3, b2f(v3.w), a3);
    }
    for (; j < end; j++) {
        int s = csr[j];
        float c = dinv[s] * dn;
        ushort4 v = ((const ushort4*)(h + (size_t)s * ODIM2))[lane];
        a0 = fmaf(c, b2f(v.x), a0); a1 = fmaf(c, b2f(v.y), a1);
        a2 = fmaf(c, b2f(v.z), a2); a3 = fmaf(c, b2f(v.w), a3);
    }

    // bring logstd (lanes 32..63) to the matching mu lane (lane-32)
    float l0 = __shfl(a0, lane | 32);
    float l1 = __shfl(a1, lane | 32);
    float l2 = __shfl(a2, lane | 32);
    float l3 = __shfl(a3, lane | 32);

    if (lane < 32) {
        int c = lane * 4;
        float4 ep = *(const float4*)(eps + (size_t)n * OUT_DIM + c);
        float4 bm = *(const float4*)(bmu + c);
        float4 bl = *(const float4*)(bls + c);
        float4 o;
        o.x = a0 + bm.x + ep.x * expf(fminf(l0 + bl.x, MAX_LOGSTD));
        o.y = a1 + bm.y + ep.y * expf(fminf(l1 + bl.y, MAX_LOGSTD));
        o.z = a2 + bm.z + ep.z * expf(fminf(l2 + bl.z, MAX_LOGSTD));
        o.w = a3 + bm.w + ep.w * expf(fminf(l3 + bl.w, MAX_LOGSTD));
        *(float4*)(z + (size_t)n * OUT_DIM + c) = o;
    }
}

extern "C" void kernel_launch(void* const* d_in, const int* in_sizes, int n_in,
                              void* d_out, int out_size, void* d_ws, size_t ws_size,
                              hipStream_t stream) {
    const float* x   = (const float*)d_in[0];
    const int*   ei  = (const int*)  d_in[1];
    const float* Wmu = (const float*)d_in[2];
    const float* bmu = (const float*)d_in[3];
    const float* Wls = (const float*)d_in[4];
    const float* bls = (const float*)d_in[5];
    const float* eps = (const float*)d_in[6];
    float* z = (float*)d_out;

    char* ws = (char*)d_ws;
    size_t off = 0;
    auto alloc = [&](size_t bytes) {
        void* p = ws + off;
        off += (bytes + 255) & ~(size_t)255;
        return p;
    };
    int*   ei32      = (int*)  alloc((size_t)2 * NEDGE * 4);
    int*   cnt       = (int*)  alloc((size_t)N_NODES * 4);
    float* dinv      = (float*)alloc((size_t)N_NODES * 4);
    int*   row_start = (int*)  alloc((size_t)(N_NODES + 1) * 4);
    int*   pos       = (int*)  alloc((size_t)N_NODES * 4);
    int*   csr       = (int*)  alloc((size_t)NEDGE * 4);
    unsigned short* h = (unsigned short*)alloc((size_t)N_NODES * ODIM2 * 2);

    hipMemsetAsync(cnt, 0, N_NODES * sizeof(int), stream);

    k_edges <<<(2 * NEDGE + 255) / 256, 256, 0, stream>>>(ei, ei32);
    k_count <<<(NEDGE + 255) / 256,     256, 0, stream>>>(ei32, cnt);
    k_dinv  <<<(N_NODES + 255) / 256,   256, 0, stream>>>(cnt, dinv);
    k_scan  <<<1, SCAN_THREADS,            0, stream>>>(cnt, row_start, pos);
    k_fill  <<<(NEDGE + 255) / 256,     256, 0, stream>>>(ei32, pos, csr);
    k_gemm  <<<N_NODES / 16,            256, 0, stream>>>(x, Wmu, Wls, h);
    k_gather<<<N_NODES / 4,             256, 0, stream>>>(row_start, csr, dinv, h,
                                                          eps, bmu, bls, z);
}

// Round 3
// 355.548 us; speedup vs baseline: 8.0477x; 1.1144x over previous
//
#include <hip/hip_runtime.h>
#include <hip/hip_bf16.h>

#define N_NODES 50000
#define IN_DIM 256
#define OUT_DIM 128
#define ODIM2 256        // mu(128) + logstd(128) concatenated
#define NEDGE 800000
#define MAX_LOGSTD 10.0f
#define SCAN_THREADS 1024
#define SCAN_CHUNK 49    // 1024*49 = 50176 >= 50000

typedef short bf16x8 __attribute__((ext_vector_type(8)));
typedef float f32x4  __attribute__((ext_vector_type(4)));

__device__ __forceinline__ float b2f(unsigned short u) {
    union { unsigned int i; float f; } v; v.i = ((unsigned int)u) << 16; return v.f;
}
__device__ __forceinline__ unsigned short f2b(float f) {
    union { float f; unsigned int i; } v; v.f = f;
    unsigned int x = v.i;
    unsigned int r = (x + 0x7fffu + ((x >> 16) & 1u)) >> 16;
    return (unsigned short)r;
}

// Normalize edge_index to int32 in ws. Detect int64 (harness may deliver either):
// as int32 words, int64 values < 2^31 appear as (lo, 0) pairs -> odd words all zero.
__global__ void k_edges(const int* __restrict__ raw, int* __restrict__ ei32) {
    bool is64 = true;
    #pragma unroll
    for (int i = 0; i < 8; i++) if (raw[2 * i + 1] != 0) is64 = false;
    int idx = blockIdx.x * blockDim.x + threadIdx.x;
    if (idx < 2 * NEDGE) ei32[idx] = is64 ? raw[2 * idx] : raw[idx];
}

// Histogram of dst -> cnt[]
__global__ void k_count(const int* __restrict__ ei, int* __restrict__ cnt) {
    int e = blockIdx.x * blockDim.x + threadIdx.x;
    if (e < NEDGE) atomicAdd(&cnt[ei[NEDGE + e]], 1);
}

__global__ void k_dinv(const int* __restrict__ cnt, float* __restrict__ dinv) {
    int n = blockIdx.x * blockDim.x + threadIdx.x;
    if (n < N_NODES) dinv[n] = rsqrtf((float)cnt[n] + 1.0f);
}

// Single-block exclusive scan: row_start[N+1], pos[] = copy of row_start[0..N-1]
__global__ __launch_bounds__(SCAN_THREADS) void k_scan(
    const int* __restrict__ cnt, int* __restrict__ row_start, int* __restrict__ pos)
{
    __shared__ int part[SCAN_THREADS];
    int t = threadIdx.x;
    int base = t * SCAN_CHUNK;
    int s = 0;
    for (int i = 0; i < SCAN_CHUNK; i++) {
        int idx = base + i;
        if (idx < N_NODES) s += cnt[idx];
    }
    part[t] = s;
    __syncthreads();
    for (int off = 1; off < SCAN_THREADS; off <<= 1) {
        int v = (t >= off) ? part[t - off] : 0;
        __syncthreads();
        part[t] += v;
        __syncthreads();
    }
    int run = (t == 0) ? 0 : part[t - 1];
    for (int i = 0; i < SCAN_CHUNK; i++) {
        int idx = base + i;
        if (idx < N_NODES) {
            row_start[idx] = run;
            pos[idx] = run;
            run += cnt[idx];
        }
    }
    if (t == SCAN_THREADS - 1) row_start[N_NODES] = run;
}

// Bin edges by dst: csr_src[row_start[dst] + k] = src
__global__ void k_fill(const int* __restrict__ ei, int* __restrict__ pos,
                       int* __restrict__ csr) {
    int e = blockIdx.x * blockDim.x + threadIdx.x;
    if (e < NEDGE) {
        int dst = ei[NEDGE + e];
        int p = atomicAdd(&pos[dst], 1);
        csr[p] = ei[e];
    }
}

// Pack concat(Wmu,Wls) [256 x 256] f32 into B-fragment-ordered bf16:
// Wp[((tile*8 + kk)*64 + lane)*8 + j] = W[kk*32 + (lane>>4)*8 + j][tile*16 + (lane&15)]
__global__ void k_wconv(const float* __restrict__ Wmu, const float* __restrict__ Wls,
                        unsigned short* __restrict__ Wp) {
    int i = blockIdx.x * blockDim.x + threadIdx.x;   // 8192 threads
    int lane = i & 63;
    int kk   = (i >> 6) & 7;
    int tile = i >> 9;
    int k0 = kk * 32 + (lane >> 4) * 8;
    int n  = tile * 16 + (lane & 15);
    const float* W = (n < 128) ? (Wmu + n) : (Wls + (n - 128));
    unsigned short o[8];
    #pragma unroll
    for (int j = 0; j < 8; j++) o[j] = f2b(W[(size_t)(k0 + j) * OUT_DIM]);
    ushort4 lo = { o[0], o[1], o[2], o[3] };
    ushort4 hi = { o[4], o[5], o[6], o[7] };
    *(ushort4*)(Wp + (size_t)i * 8)     = lo;
    *(ushort4*)(Wp + (size_t)i * 8 + 4) = hi;
}

// MFMA GEMM: h[64 rows x 256 cols] per block. 4 waves, one 16-row tile each.
// x staged to LDS as bf16 with XOR swizzle (A-frag ds_read_b128 else 16-way conflict).
__global__ __launch_bounds__(256) void k_gemm_mfma(
    const float* __restrict__ x, const unsigned short* __restrict__ Wp,
    unsigned short* __restrict__ h)
{
    __shared__ unsigned short xs[64 * 256];   // 32 KB, swizzled
    const int tid  = threadIdx.x;
    const int lane = tid & 63;
    const int w    = tid >> 6;
    const int row0 = blockIdx.x * 64;

    // stage 64x256 f32 -> bf16. thread t, iter i handles float4 #(i*256+t):
    // each wave writes one full row per iter (coalesced 1KB global read).
    #pragma unroll
    for (int i = 0; i < 16; i++) {
        int f   = i * 256 + tid;
        int row = f >> 6;
        int c4  = f & 63;
        int grow = row0 + row;
        float4 v = make_float4(0.f, 0.f, 0.f, 0.f);
        if (grow < N_NODES) v = *(const float4*)(x + (size_t)grow * IN_DIM + c4 * 4);
        ushort4 b = { f2b(v.x), f2b(v.y), f2b(v.z), f2b(v.w) };
        unsigned int byte = (unsigned)(row * 512 + c4 * 8);
        byte ^= (unsigned)((row & 7) << 4);
        *(ushort4*)((char*)xs + byte) = b;
    }
    __syncthreads();

    f32x4 acc[16];
    #pragma unroll
    for (int t = 0; t < 16; t++) acc[t] = (f32x4){0.f, 0.f, 0.f, 0.f};

    const int arow = w * 16 + (lane & 15);
    const unsigned int abase = (unsigned)(arow * 512 + (lane >> 4) * 16);
    const unsigned int axor  = (unsigned)((arow & 7) << 4);
    const bf16x8* wp = (const bf16x8*)Wp + lane;

    for (int kk = 0; kk < 8; kk++) {
        bf16x8 a = *(const bf16x8*)((const char*)xs + ((abase + kk * 64) ^ axor));
        #pragma unroll
        for (int t = 0; t < 16; t++) {
            bf16x8 b = wp[(t * 8 + kk) * 64];
            acc[t] = __builtin_amdgcn_mfma_f32_16x16x32_bf16(a, b, acc[t], 0, 0, 0);
        }
    }

    // epilogue: C/D layout col=lane&15, row=(lane>>4)*4+reg
    const int rbase = row0 + w * 16 + (lane >> 4) * 4;
    const int cl = lane & 15;
    #pragma unroll
    for (int t = 0; t < 16; t++) {
        int col = t * 16 + cl;
        #pragma unroll
        for (int r = 0; r < 4; r++) {
            int row = rbase + r;
            if (row < N_NODES) h[(size_t)row * ODIM2 + col] = f2b(acc[t][r]);
        }
    }
}

// One wave per dst node: pull all in-edges, fused self-loop + bias + reparam.
// Lane l holds h-cols l*4..l*4+3 (l<32: mu, l>=32: logstd).
__global__ __launch_bounds__(256) void k_gather(
    const int* __restrict__ row_start, const int* __restrict__ csr,
    const float* __restrict__ dinv, const unsigned short* __restrict__ h,
    const float* __restrict__ eps, const float* __restrict__ bmu,
    const float* __restrict__ bls, float* __restrict__ z)
{
    int tid  = threadIdx.x;
    int n    = blockIdx.x * 4 + (tid >> 6);
    int lane = tid & 63;
    float dn = dinv[n];

    float a0, a1, a2, a3;
    {   // self-loop: dinv^2 * h[n]
        ushort4 v = ((const ushort4*)(h + (size_t)n * ODIM2))[lane];
        float c = dn * dn;
        a0 = c * b2f(v.x); a1 = c * b2f(v.y); a2 = c * b2f(v.z); a3 = c * b2f(v.w);
    }

    int j   = row_start[n];
    int end = row_start[n + 1];
    for (; j + 4 <= end; j += 4) {
        int s0 = csr[j], s1 = csr[j + 1], s2 = csr[j + 2], s3 = csr[j + 3];
        float c0 = dinv[s0] * dn, c1 = dinv[s1] * dn;
        float c2 = dinv[s2] * dn, c3 = dinv[s3] * dn;
        ushort4 v0 = ((const ushort4*)(h + (size_t)s0 * ODIM2))[lane];
        ushort4 v1 = ((const ushort4*)(h + (size_t)s1 * ODIM2))[lane];
        ushort4 v2 = ((const ushort4*)(h + (size_t)s2 * ODIM2))[lane];
        ushort4 v3 = ((const ushort4*)(h + (size_t)s3 * ODIM2))[lane];
        a0 = fmaf(c0, b2f(v0.x), a0); a1 = fmaf(c0, b2f(v0.y), a1);
        a2 = fmaf(c0, b2f(v0.z), a2); a3 = fmaf(c0, b2f(v0.w), a3);
        a0 = fmaf(c1, b2f(v1.x), a0); a1 = fmaf(c1, b2f(v1.y), a1);
        a2 = fmaf(c1, b2f(v1.z), a2); a3 = fmaf(c1, b2f(v1.w), a3);
        a0 = fmaf(c2, b2f(v2.x), a0); a1 = fmaf(c2, b2f(v2.y), a1);
        a2 = fmaf(c2, b2f(v2.z), a2); a3 = fmaf(c2, b2f(v2.w), a3);
        a0 = fmaf(c3, b2f(v3.x), a0); a1 = fmaf(c3, b2f(v3.y), a1);
        a2 = fmaf(c3, b2f(v3.z), a2); a3 = fmaf(c3, b2f(v3.w), a3);
    }
    for (; j < end; j++) {
        int s = csr[j];
        float c = dinv[s] * dn;
        ushort4 v = ((const ushort4*)(h + (size_t)s * ODIM2))[lane];
        a0 = fmaf(c, b2f(v.x), a0); a1 = fmaf(c, b2f(v.y), a1);
        a2 = fmaf(c, b2f(v.z), a2); a3 = fmaf(c, b2f(v.w), a3);
    }

    // bring logstd (lanes 32..63) to the matching mu lane (lane-32)
    float l0 = __shfl(a0, lane | 32);
    float l1 = __shfl(a1, lane | 32);
    float l2 = __shfl(a2, lane | 32);
    float l3 = __shfl(a3, lane | 32);

    if (lane < 32) {
        int c = lane * 4;
        float4 ep = *(const float4*)(eps + (size_t)n * OUT_DIM + c);
        float4 bm = *(const float4*)(bmu + c);
        float4 bl = *(const float4*)(bls + c);
        float4 o;
        o.x = a0 + bm.x + ep.x * expf(fminf(l0 + bl.x, MAX_LOGSTD));
        o.y = a1 + bm.y + ep.y * expf(fminf(l1 + bl.y, MAX_LOGSTD));
        o.z = a2 + bm.z + ep.z * expf(fminf(l2 + bl.z, MAX_LOGSTD));
        o.w = a3 + bm.w + ep.w * expf(fminf(l3 + bl.w, MAX_LOGSTD));
        *(float4*)(z + (size_t)n * OUT_DIM + c) = o;
    }
}

extern "C" void kernel_launch(void* const* d_in, const int* in_sizes, int n_in,
                              void* d_out, int out_size, void* d_ws, size_t ws_size,
                              hipStream_t stream) {
    const float* x   = (const float*)d_in[0];
    const int*   ei  = (const int*)  d_in[1];
    const float* Wmu = (const float*)d_in[2];
    const float* bmu = (const float*)d_in[3];
    const float* Wls = (const float*)d_in[4];
    const float* bls = (const float*)d_in[5];
    const float* eps = (const float*)d_in[6];
    float* z = (float*)d_out;

    char* ws = (char*)d_ws;
    size_t off = 0;
    auto alloc = [&](size_t bytes) {
        void* p = ws + off;
        off += (bytes + 255) & ~(size_t)255;
        return p;
    };
    int*   ei32      = (int*)  alloc((size_t)2 * NEDGE * 4);
    int*   cnt       = (int*)  alloc((size_t)N_NODES * 4);
    float* dinv      = (float*)alloc((size_t)N_NODES * 4);
    int*   row_start = (int*)  alloc((size_t)(N_NODES + 1) * 4);
    int*   pos       = (int*)  alloc((size_t)N_NODES * 4);
    int*   csr       = (int*)  alloc((size_t)NEDGE * 4);
    unsigned short* h  = (unsigned short*)alloc((size_t)N_NODES * ODIM2 * 2);
    unsigned short* Wp = (unsigned short*)alloc((size_t)65536 * 2);

    hipMemsetAsync(cnt, 0, N_NODES * sizeof(int), stream);

    k_edges <<<(2 * NEDGE + 255) / 256, 256, 0, stream>>>(ei, ei32);
    k_count <<<(NEDGE + 255) / 256,     256, 0, stream>>>(ei32, cnt);
    k_dinv  <<<(N_NODES + 255) / 256,   256, 0, stream>>>(cnt, dinv);
    k_scan  <<<1, SCAN_THREADS,            0, stream>>>(cnt, row_start, pos);
    k_fill  <<<(NEDGE + 255) / 256,     256, 0, stream>>>(ei32, pos, csr);
    k_wconv <<<32,                      256, 0, stream>>>(Wmu, Wls, Wp);
    k_gemm_mfma<<<(N_NODES + 63) / 64,  256, 0, stream>>>(x, Wp, h);
    k_gather<<<N_NODES / 4,             256, 0, stream>>>(row_start, csr, dinv, h,
                                                          eps, bmu, bls, z);
}

// Round 4
// 232.127 us; speedup vs baseline: 12.3266x; 1.5317x over previous
//
#include <hip/hip_runtime.h>
#include <hip/hip_bf16.h>

#define N_NODES 50000
#define IN_DIM 256
#define OUT_DIM 128
#define ODIM2 256        // mu(128) + logstd(128) concatenated
#define NEDGE 800000
#define MAX_LOGSTD 10.0f
#define NBLK 196         // ceil(50000/256)

typedef short bf16x8 __attribute__((ext_vector_type(8)));
typedef float f32x4  __attribute__((ext_vector_type(4)));

__device__ __forceinline__ float b2f(unsigned short u) {
    union { unsigned int i; float f; } v; v.i = ((unsigned int)u) << 16; return v.f;
}
__device__ __forceinline__ unsigned short f2b(float f) {
    union { float f; unsigned int i; } v; v.f = f;
    unsigned int x = v.i;
    unsigned int r = (x + 0x7fffu + ((x >> 16) & 1u)) >> 16;
    return (unsigned short)r;
}

// Convert edges to int32 (detect int64 layout: odd words all zero) + dst histogram.
__global__ void k_conv_count(const int* __restrict__ raw, int* __restrict__ ei32,
                             int* __restrict__ cnt) {
    bool is64 = true;
    #pragma unroll
    for (int i = 0; i < 8; i++) if (raw[2 * i + 1] != 0) is64 = false;
    int e = blockIdx.x * blockDim.x + threadIdx.x;
    if (e < NEDGE) {
        int src = is64 ? raw[2 * e] : raw[e];
        int dst = is64 ? raw[2 * (NEDGE + e)] : raw[NEDGE + e];
        ei32[e] = src;
        ei32[NEDGE + e] = dst;
        atomicAdd(&cnt[dst], 1);
    }
}

// Phase 1: per-block (256 counts) sums
__global__ __launch_bounds__(256) void k_blocksum(const int* __restrict__ cnt,
                                                  int* __restrict__ bsum) {
    int idx = blockIdx.x * 256 + threadIdx.x;
    int v = (idx < N_NODES) ? cnt[idx] : 0;
    #pragma unroll
    for (int o = 32; o > 0; o >>= 1) v += __shfl_down(v, o);
    __shared__ int wsum[4];
    int lane = threadIdx.x & 63, w = threadIdx.x >> 6;
    if (lane == 0) wsum[w] = v;
    __syncthreads();
    if (threadIdx.x == 0) bsum[blockIdx.x] = wsum[0] + wsum[1] + wsum[2] + wsum[3];
}

// Phase 2: scan 196 block sums -> exclusive block offsets
__global__ __launch_bounds__(256) void k_scanblocks(const int* __restrict__ bsum,
                                                    int* __restrict__ boff) {
    __shared__ int s[256];
    int t = threadIdx.x;
    s[t] = (t < NBLK) ? bsum[t] : 0;
    __syncthreads();
    for (int o = 1; o < 256; o <<= 1) {
        int v = (t >= o) ? s[t - o] : 0;
        __syncthreads();
        s[t] += v;
        __syncthreads();
    }
    if (t < NBLK) boff[t] = (t == 0) ? 0 : s[t - 1];
}

// Phase 3: in-block exclusive scan + offset -> row_start, pos; dinv fused.
__global__ __launch_bounds__(256) void k_apply(const int* __restrict__ cnt,
                                               const int* __restrict__ boff,
                                               int* __restrict__ row_start,
                                               int* __restrict__ pos,
                                               float* __restrict__ dinv) {
    __shared__ int s[256];
    int t = threadIdx.x;
    int idx = blockIdx.x * 256 + t;
    int c = (idx < N_NODES) ? cnt[idx] : 0;
    s[t] = c;
    __syncthreads();
    for (int o = 1; o < 256; o <<= 1) {
        int v = (t >= o) ? s[t - o] : 0;
        __syncthreads();
        s[t] += v;
        __syncthreads();
    }
    int excl = boff[blockIdx.x] + s[t] - c;
    if (idx < N_NODES) {
        row_start[idx] = excl;
        pos[idx] = excl;
        dinv[idx] = rsqrtf((float)c + 1.0f);
    }
    if (idx == N_NODES - 1) row_start[N_NODES] = NEDGE;
}

// Bin edges by dst: csr_src[row_start[dst] + k] = src
__global__ void k_fill(const int* __restrict__ ei, int* __restrict__ pos,
                       int* __restrict__ csr) {
    int e = blockIdx.x * blockDim.x + threadIdx.x;
    if (e < NEDGE) {
        int dst = ei[NEDGE + e];
        int p = atomicAdd(&pos[dst], 1);
        csr[p] = ei[e];
    }
}

// Pack concat(Wmu,Wls) [256 x 256] f32 into B-fragment-ordered bf16:
// Wp[((tile*8 + kk)*64 + lane)*8 + j] = W[kk*32 + (lane>>4)*8 + j][tile*16 + (lane&15)]
__global__ void k_wconv(const float* __restrict__ Wmu, const float* __restrict__ Wls,
                        unsigned short* __restrict__ Wp) {
    int i = blockIdx.x * blockDim.x + threadIdx.x;   // 8192 threads
    int lane = i & 63;
    int kk   = (i >> 6) & 7;
    int tile = i >> 9;
    int k0 = kk * 32 + (lane >> 4) * 8;
    int n  = tile * 16 + (lane & 15);
    const float* W = (n < 128) ? (Wmu + n) : (Wls + (n - 128));
    unsigned short o[8];
    #pragma unroll
    for (int j = 0; j < 8; j++) o[j] = f2b(W[(size_t)(k0 + j) * OUT_DIM]);
    ushort4 lo = { o[0], o[1], o[2], o[3] };
    ushort4 hi = { o[4], o[5], o[6], o[7] };
    *(ushort4*)(Wp + (size_t)i * 8)     = lo;
    *(ushort4*)(Wp + (size_t)i * 8 + 4) = hi;
}

// MFMA GEMM: h[64 rows x 256 cols] per block. 4 waves, one 16-row tile each.
__global__ __launch_bounds__(256) void k_gemm_mfma(
    const float* __restrict__ x, const unsigned short* __restrict__ Wp,
    unsigned short* __restrict__ h)
{
    __shared__ unsigned short xs[64 * 256];   // 32 KB, swizzled
    const int tid  = threadIdx.x;
    const int lane = tid & 63;
    const int w    = tid >> 6;
    const int row0 = blockIdx.x * 64;

    #pragma unroll
    for (int i = 0; i < 16; i++) {
        int f   = i * 256 + tid;
        int row = f >> 6;
        int c4  = f & 63;
        int grow = row0 + row;
        float4 v = make_float4(0.f, 0.f, 0.f, 0.f);
        if (grow < N_NODES) v = *(const float4*)(x + (size_t)grow * IN_DIM + c4 * 4);
        ushort4 b = { f2b(v.x), f2b(v.y), f2b(v.z), f2b(v.w) };
        unsigned int byte = (unsigned)(row * 512 + c4 * 8);
        byte ^= (unsigned)((row & 7) << 4);
        *(ushort4*)((char*)xs + byte) = b;
    }
    __syncthreads();

    f32x4 acc[16];
    #pragma unroll
    for (int t = 0; t < 16; t++) acc[t] = (f32x4){0.f, 0.f, 0.f, 0.f};

    const int arow = w * 16 + (lane & 15);
    const unsigned int abase = (unsigned)(arow * 512 + (lane >> 4) * 16);
    const unsigned int axor  = (unsigned)((arow & 7) << 4);
    const bf16x8* wp = (const bf16x8*)Wp + lane;

    for (int kk = 0; kk < 8; kk++) {
        bf16x8 a = *(const bf16x8*)((const char*)xs + ((abase + kk * 64) ^ axor));
        #pragma unroll
        for (int t = 0; t < 16; t++) {
            bf16x8 b = wp[(t * 8 + kk) * 64];
            acc[t] = __builtin_amdgcn_mfma_f32_16x16x32_bf16(a, b, acc[t], 0, 0, 0);
        }
    }

    const int rbase = row0 + w * 16 + (lane >> 4) * 4;
    const int cl = lane & 15;
    #pragma unroll
    for (int t = 0; t < 16; t++) {
        int col = t * 16 + cl;
        #pragma unroll
        for (int r = 0; r < 4; r++) {
            int row = rbase + r;
            if (row < N_NODES) h[(size_t)row * ODIM2 + col] = f2b(acc[t][r]);
        }
    }
}

// One wave per dst node: pull all in-edges, fused self-loop + bias + reparam.
__global__ __launch_bounds__(256) void k_gather(
    const int* __restrict__ row_start, const int* __restrict__ csr,
    const float* __restrict__ dinv, const unsigned short* __restrict__ h,
    const float* __restrict__ eps, const float* __restrict__ bmu,
    const float* __restrict__ bls, float* __restrict__ z)
{
    int tid  = threadIdx.x;
    int n    = blockIdx.x * 4 + (tid >> 6);
    int lane = tid & 63;
    float dn = dinv[n];

    float a0, a1, a2, a3;
    {   // self-loop: dinv^2 * h[n]
        ushort4 v = ((const ushort4*)(h + (size_t)n * ODIM2))[lane];
        float c = dn * dn;
        a0 = c * b2f(v.x); a1 = c * b2f(v.y); a2 = c * b2f(v.z); a3 = c * b2f(v.w);
    }

    int j   = row_start[n];
    int end = row_start[n + 1];
    for (; j + 4 <= end; j += 4) {
        int s0 = csr[j], s1 = csr[j + 1], s2 = csr[j + 2], s3 = csr[j + 3];
        float c0 = dinv[s0] * dn, c1 = dinv[s1] * dn;
        float c2 = dinv[s2] * dn, c3 = dinv[s3] * dn;
        ushort4 v0 = ((const ushort4*)(h + (size_t)s0 * ODIM2))[lane];
        ushort4 v1 = ((const ushort4*)(h + (size_t)s1 * ODIM2))[lane];
        ushort4 v2 = ((const ushort4*)(h + (size_t)s2 * ODIM2))[lane];
        ushort4 v3 = ((const ushort4*)(h + (size_t)s3 * ODIM2))[lane];
        a0 = fmaf(c0, b2f(v0.x), a0); a1 = fmaf(c0, b2f(v0.y), a1);
        a2 = fmaf(c0, b2f(v0.z), a2); a3 = fmaf(c0, b2f(v0.w), a3);
        a0 = fmaf(c1, b2f(v1.x), a0); a1 = fmaf(c1, b2f(v1.y), a1);
        a2 = fmaf(c1, b2f(v1.z), a2); a3 = fmaf(c1, b2f(v1.w), a3);
        a0 = fmaf(c2, b2f(v2.x), a0); a1 = fmaf(c2, b2f(v2.y), a1);
        a2 = fmaf(c2, b2f(v2.z), a2); a3 = fmaf(c2, b2f(v2.w), a3);
        a0 = fmaf(c3, b2f(v3.x), a0); a1 = fmaf(c3, b2f(v3.y), a1);
        a2 = fmaf(c3, b2f(v3.z), a2); a3 = fmaf(c3, b2f(v3.w), a3);
    }
    for (; j < end; j++) {
        int s = csr[j];
        float c = dinv[s] * dn;
        ushort4 v = ((const ushort4*)(h + (size_t)s * ODIM2))[lane];
        a0 = fmaf(c, b2f(v.x), a0); a1 = fmaf(c, b2f(v.y), a1);
        a2 = fmaf(c, b2f(v.z), a2); a3 = fmaf(c, b2f(v.w), a3);
    }

    float l0 = __shfl(a0, lane | 32);
    float l1 = __shfl(a1, lane | 32);
    float l2 = __shfl(a2, lane | 32);
    float l3 = __shfl(a3, lane | 32);

    if (lane < 32) {
        int c = lane * 4;
        float4 ep = *(const float4*)(eps + (size_t)n * OUT_DIM + c);
        float4 bm = *(const float4*)(bmu + c);
        float4 bl = *(const float4*)(bls + c);
        float4 o;
        o.x = a0 + bm.x + ep.x * expf(fminf(l0 + bl.x, MAX_LOGSTD));
        o.y = a1 + bm.y + ep.y * expf(fminf(l1 + bl.y, MAX_LOGSTD));
        o.z = a2 + bm.z + ep.z * expf(fminf(l2 + bl.z, MAX_LOGSTD));
        o.w = a3 + bm.w + ep.w * expf(fminf(l3 + bl.w, MAX_LOGSTD));
        *(float4*)(z + (size_t)n * OUT_DIM + c) = o;
    }
}

extern "C" void kernel_launch(void* const* d_in, const int* in_sizes, int n_in,
                              void* d_out, int out_size, void* d_ws, size_t ws_size,
                              hipStream_t stream) {
    const float* x   = (const float*)d_in[0];
    const int*   ei  = (const int*)  d_in[1];
    const float* Wmu = (const float*)d_in[2];
    const float* bmu = (const float*)d_in[3];
    const float* Wls = (const float*)d_in[4];
    const float* bls = (const float*)d_in[5];
    const float* eps = (const float*)d_in[6];
    float* z = (float*)d_out;

    char* ws = (char*)d_ws;
    size_t off = 0;
    auto alloc = [&](size_t bytes) {
        void* p = ws + off;
        off += (bytes + 255) & ~(size_t)255;
        return p;
    };
    int*   ei32      = (int*)  alloc((size_t)2 * NEDGE * 4);
    int*   cnt       = (int*)  alloc((size_t)N_NODES * 4);
    float* dinv      = (float*)alloc((size_t)N_NODES * 4);
    int*   row_start = (int*)  alloc((size_t)(N_NODES + 1) * 4);
    int*   pos       = (int*)  alloc((size_t)N_NODES * 4);
    int*   csr       = (int*)  alloc((size_t)NEDGE * 4);
    int*   bsum      = (int*)  alloc((size_t)NBLK * 4);
    int*   boff      = (int*)  alloc((size_t)NBLK * 4);
    unsigned short* h  = (unsigned short*)alloc((size_t)N_NODES * ODIM2 * 2);
    unsigned short* Wp = (unsigned short*)alloc((size_t)65536 * 2);

    hipMemsetAsync(cnt, 0, N_NODES * sizeof(int), stream);

    k_conv_count<<<(NEDGE + 255) / 256, 256, 0, stream>>>(ei, ei32, cnt);
    k_blocksum  <<<NBLK,                256, 0, stream>>>(cnt, bsum);
    k_scanblocks<<<1,                   256, 0, stream>>>(bsum, boff);
    k_apply     <<<NBLK,                256, 0, stream>>>(cnt, boff, row_start, pos, dinv);
    k_fill      <<<(NEDGE + 255) / 256, 256, 0, stream>>>(ei32, pos, csr);
    k_wconv     <<<32,                  256, 0, stream>>>(Wmu, Wls, Wp);
    k_gemm_mfma <<<(N_NODES + 63) / 64, 256, 0, stream>>>(x, Wp, h);
    k_gather    <<<N_NODES / 4,         256, 0, stream>>>(row_start, csr, dinv, h,
                                                          eps, bmu, bls, z);
}

// Round 5
// 190.254 us; speedup vs baseline: 15.0395x; 1.2201x over previous
//
#include <hip/hip_runtime.h>
#include <hip/hip_bf16.h>

#define N_NODES 50000
#define IN_DIM 256
#define OUT_DIM 128
#define ODIM2 256        // mu(128) + logstd(128) concatenated
#define NEDGE 800000
#define MAX_LOGSTD 10.0f
#define NBLK 196         // ceil(50000/256)

typedef short bf16x8 __attribute__((ext_vector_type(8)));
typedef float f32x4  __attribute__((ext_vector_type(4)));

__device__ __forceinline__ float b2f(unsigned short u) {
    union { unsigned int i; float f; } v; v.i = ((unsigned int)u) << 16; return v.f;
}
__device__ __forceinline__ unsigned short f2b(float f) {
    union { float f; unsigned int i; } v; v.f = f;
    unsigned int x = v.i;
    unsigned int r = (x + 0x7fffu + ((x >> 16) & 1u)) >> 16;
    return (unsigned short)r;
}

// Convert edges to int32 (detect int64 layout: odd words all zero) + dst histogram.
__global__ void k_conv_count(const int* __restrict__ raw, int* __restrict__ ei32,
                             int* __restrict__ cnt) {
    bool is64 = true;
    #pragma unroll
    for (int i = 0; i < 8; i++) if (raw[2 * i + 1] != 0) is64 = false;
    int e = blockIdx.x * blockDim.x + threadIdx.x;
    if (e < NEDGE) {
        int src = is64 ? raw[2 * e] : raw[e];
        int dst = is64 ? raw[2 * (NEDGE + e)] : raw[NEDGE + e];
        ei32[e] = src;
        ei32[NEDGE + e] = dst;
        atomicAdd(&cnt[dst], 1);
    }
}

// Phase 1: per-block (256 counts) sums
__global__ __launch_bounds__(256) void k_blocksum(const int* __restrict__ cnt,
                                                  int* __restrict__ bsum) {
    int idx = blockIdx.x * 256 + threadIdx.x;
    int v = (idx < N_NODES) ? cnt[idx] : 0;
    #pragma unroll
    for (int o = 32; o > 0; o >>= 1) v += __shfl_down(v, o);
    __shared__ int wsum[4];
    int lane = threadIdx.x & 63, w = threadIdx.x >> 6;
    if (lane == 0) wsum[w] = v;
    __syncthreads();
    if (threadIdx.x == 0) bsum[blockIdx.x] = wsum[0] + wsum[1] + wsum[2] + wsum[3];
}

// Phase 2: scan 196 block sums -> exclusive block offsets
__global__ __launch_bounds__(256) void k_scanblocks(const int* __restrict__ bsum,
                                                    int* __restrict__ boff) {
    __shared__ int s[256];
    int t = threadIdx.x;
    s[t] = (t < NBLK) ? bsum[t] : 0;
    __syncthreads();
    for (int o = 1; o < 256; o <<= 1) {
        int v = (t >= o) ? s[t - o] : 0;
        __syncthreads();
        s[t] += v;
        __syncthreads();
    }
    if (t < NBLK) boff[t] = (t == 0) ? 0 : s[t - 1];
}

// Phase 3: in-block exclusive scan + offset -> row_start, pos; dinv fused.
__global__ __launch_bounds__(256) void k_apply(const int* __restrict__ cnt,
                                               const int* __restrict__ boff,
                                               int* __restrict__ row_start,
                                               int* __restrict__ pos,
                                               float* __restrict__ dinv) {
    __shared__ int s[256];
    int t = threadIdx.x;
    int idx = blockIdx.x * 256 + t;
    int c = (idx < N_NODES) ? cnt[idx] : 0;
    s[t] = c;
    __syncthreads();
    for (int o = 1; o < 256; o <<= 1) {
        int v = (t >= o) ? s[t - o] : 0;
        __syncthreads();
        s[t] += v;
        __syncthreads();
    }
    int excl = boff[blockIdx.x] + s[t] - c;
    if (idx < N_NODES) {
        row_start[idx] = excl;
        pos[idx] = excl;
        dinv[idx] = rsqrtf((float)c + 1.0f);
    }
    if (idx == N_NODES - 1) row_start[N_NODES] = NEDGE;
}

// Bin edges by dst: csr_src[row_start[dst] + k] = src
__global__ void k_fill(const int* __restrict__ ei, int* __restrict__ pos,
                       int* __restrict__ csr) {
    int e = blockIdx.x * blockDim.x + threadIdx.x;
    if (e < NEDGE) {
        int dst = ei[NEDGE + e];
        int p = atomicAdd(&pos[dst], 1);
        csr[p] = ei[e];
    }
}

// Pack concat(Wmu,Wls) [256 x 256] f32 into B-fragment-ordered bf16:
// Wp[((tile*8 + kk)*64 + lane)*8 + j] = W[kk*32 + (lane>>4)*8 + j][tile*16 + (lane&15)]
__global__ void k_wconv(const float* __restrict__ Wmu, const float* __restrict__ Wls,
                        unsigned short* __restrict__ Wp) {
    int i = blockIdx.x * blockDim.x + threadIdx.x;   // 8192 threads
    int lane = i & 63;
    int kk   = (i >> 6) & 7;
    int tile = i >> 9;
    int k0 = kk * 32 + (lane >> 4) * 8;
    int n  = tile * 16 + (lane & 15);
    const float* W = (n < 128) ? (Wmu + n) : (Wls + (n - 128));
    unsigned short o[8];
    #pragma unroll
    for (int j = 0; j < 8; j++) o[j] = f2b(W[(size_t)(k0 + j) * OUT_DIM]);
    ushort4 lo = { o[0], o[1], o[2], o[3] };
    ushort4 hi = { o[4], o[5], o[6], o[7] };
    *(ushort4*)(Wp + (size_t)i * 8)     = lo;
    *(ushort4*)(Wp + (size_t)i * 8 + 4) = hi;
}

// MFMA GEMM: h[64 rows x 256 cols] per block. 4 waves; wave w owns col-tiles
// 4w..4w+3 (64 cols) with B fragments RESIDENT in registers (32 x bf16x8),
// and sweeps all 4 row-subtiles. Inner loop: ds_read_b128 + MFMA only.
__global__ __launch_bounds__(256, 2) void k_gemm_mfma(
    const float* __restrict__ x, const unsigned short* __restrict__ Wp,
    unsigned short* __restrict__ h)
{
    __shared__ unsigned short xs[64 * 256];   // 32 KB, swizzled
    const int tid  = threadIdx.x;
    const int lane = tid & 63;
    const int w    = tid >> 6;
    const int row0 = blockIdx.x * 64;

    // B fragments for this wave's 4 col-tiles, all 8 k-steps: loaded ONCE.
    // Issued before staging so the L2 latency hides under the x loads.
    bf16x8 breg[4][8];
    #pragma unroll
    for (int t = 0; t < 4; t++)
        #pragma unroll
        for (int kk = 0; kk < 8; kk++)
            breg[t][kk] = ((const bf16x8*)Wp)[((4 * w + t) * 8 + kk) * 64 + lane];

    // stage 64x256 f32 -> bf16 (XOR-swizzled rows)
    #pragma unroll
    for (int i = 0; i < 16; i++) {
        int f   = i * 256 + tid;
        int row = f >> 6;
        int c4  = f & 63;
        int grow = row0 + row;
        float4 v = make_float4(0.f, 0.f, 0.f, 0.f);
        if (grow < N_NODES) v = *(const float4*)(x + (size_t)grow * IN_DIM + c4 * 4);
        ushort4 b = { f2b(v.x), f2b(v.y), f2b(v.z), f2b(v.w) };
        unsigned int byte = (unsigned)(row * 512 + c4 * 8);
        byte ^= (unsigned)((row & 7) << 4);
        *(ushort4*)((char*)xs + byte) = b;
    }
    __syncthreads();

    #pragma unroll
    for (int sub = 0; sub < 4; sub++) {
        const int arow = sub * 16 + (lane & 15);
        const unsigned int abase = (unsigned)(arow * 512 + (lane >> 4) * 16);
        const unsigned int axor  = (unsigned)((arow & 7) << 4);

        bf16x8 a[8];
        #pragma unroll
        for (int kk = 0; kk < 8; kk++)
            a[kk] = *(const bf16x8*)((const char*)xs + ((abase + kk * 64) ^ axor));

        f32x4 acc[4];
        #pragma unroll
        for (int t = 0; t < 4; t++) acc[t] = (f32x4){0.f, 0.f, 0.f, 0.f};

        #pragma unroll
        for (int kk = 0; kk < 8; kk++)
            #pragma unroll
            for (int t = 0; t < 4; t++)
                acc[t] = __builtin_amdgcn_mfma_f32_16x16x32_bf16(a[kk], breg[t][kk],
                                                                 acc[t], 0, 0, 0);

        // C/D layout: col=lane&15, row=(lane>>4)*4+reg
        const int rbase = row0 + sub * 16 + (lane >> 4) * 4;
        const int cl = lane & 15;
        #pragma unroll
        for (int t = 0; t < 4; t++) {
            int col = (4 * w + t) * 16 + cl;
            #pragma unroll
            for (int r = 0; r < 4; r++) {
                int row = rbase + r;
                if (row < N_NODES) h[(size_t)row * ODIM2 + col] = f2b(acc[t][r]);
            }
        }
    }
}

// One wave per dst node: pull all in-edges, fused self-loop + bias + reparam.
__global__ __launch_bounds__(256) void k_gather(
    const int* __restrict__ row_start, const int* __restrict__ csr,
    const float* __restrict__ dinv, const unsigned short* __restrict__ h,
    const float* __restrict__ eps, const float* __restrict__ bmu,
    const float* __restrict__ bls, float* __restrict__ z)
{
    int tid  = threadIdx.x;
    int n    = blockIdx.x * 4 + (tid >> 6);
    int lane = tid & 63;
    float dn = dinv[n];

    float a0, a1, a2, a3;
    {   // self-loop: dinv^2 * h[n]
        ushort4 v = ((const ushort4*)(h + (size_t)n * ODIM2))[lane];
        float c = dn * dn;
        a0 = c * b2f(v.x); a1 = c * b2f(v.y); a2 = c * b2f(v.z); a3 = c * b2f(v.w);
    }

    int j   = row_start[n];
    int end = row_start[n + 1];
    for (; j + 4 <= end; j += 4) {
        int s0 = csr[j], s1 = csr[j + 1], s2 = csr[j + 2], s3 = csr[j + 3];
        float c0 = dinv[s0] * dn, c1 = dinv[s1] * dn;
        float c2 = dinv[s2] * dn, c3 = dinv[s3] * dn;
        ushort4 v0 = ((const ushort4*)(h + (size_t)s0 * ODIM2))[lane];
        ushort4 v1 = ((const ushort4*)(h + (size_t)s1 * ODIM2))[lane];
        ushort4 v2 = ((const ushort4*)(h + (size_t)s2 * ODIM2))[lane];
        ushort4 v3 = ((const ushort4*)(h + (size_t)s3 * ODIM2))[lane];
        a0 = fmaf(c0, b2f(v0.x), a0); a1 = fmaf(c0, b2f(v0.y), a1);
        a2 = fmaf(c0, b2f(v0.z), a2); a3 = fmaf(c0, b2f(v0.w), a3);
        a0 = fmaf(c1, b2f(v1.x), a0); a1 = fmaf(c1, b2f(v1.y), a1);
        a2 = fmaf(c1, b2f(v1.z), a2); a3 = fmaf(c1, b2f(v1.w), a3);
        a0 = fmaf(c2, b2f(v2.x), a0); a1 = fmaf(c2, b2f(v2.y), a1);
        a2 = fmaf(c2, b2f(v2.z), a2); a3 = fmaf(c2, b2f(v2.w), a3);
        a0 = fmaf(c3, b2f(v3.x), a0); a1 = fmaf(c3, b2f(v3.y), a1);
        a2 = fmaf(c3, b2f(v3.z), a2); a3 = fmaf(c3, b2f(v3.w), a3);
    }
    for (; j < end; j++) {
        int s = csr[j];
        float c = dinv[s] * dn;
        ushort4 v = ((const ushort4*)(h + (size_t)s * ODIM2))[lane];
        a0 = fmaf(c, b2f(v.x), a0); a1 = fmaf(c, b2f(v.y), a1);
        a2 = fmaf(c, b2f(v.z), a2); a3 = fmaf(c, b2f(v.w), a3);
    }

    float l0 = __shfl(a0, lane | 32);
    float l1 = __shfl(a1, lane | 32);
    float l2 = __shfl(a2, lane | 32);
    float l3 = __shfl(a3, lane | 32);

    if (lane < 32) {
        int c = lane * 4;
        float4 ep = *(const float4*)(eps + (size_t)n * OUT_DIM + c);
        float4 bm = *(const float4*)(bmu + c);
        float4 bl = *(const float4*)(bls + c);
        float4 o;
        o.x = a0 + bm.x + ep.x * expf(fminf(l0 + bl.x, MAX_LOGSTD));
        o.y = a1 + bm.y + ep.y * expf(fminf(l1 + bl.y, MAX_LOGSTD));
        o.z = a2 + bm.z + ep.z * expf(fminf(l2 + bl.z, MAX_LOGSTD));
        o.w = a3 + bm.w + ep.w * expf(fminf(l3 + bl.w, MAX_LOGSTD));
        *(float4*)(z + (size_t)n * OUT_DIM + c) = o;
    }
}

extern "C" void kernel_launch(void* const* d_in, const int* in_sizes, int n_in,
                              void* d_out, int out_size, void* d_ws, size_t ws_size,
                              hipStream_t stream) {
    const float* x   = (const float*)d_in[0];
    const int*   ei  = (const int*)  d_in[1];
    const float* Wmu = (const float*)d_in[2];
    const float* bmu = (const float*)d_in[3];
    const float* Wls = (const float*)d_in[4];
    const float* bls = (const float*)d_in[5];
    const float* eps = (const float*)d_in[6];
    float* z = (float*)d_out;

    char* ws = (char*)d_ws;
    size_t off = 0;
    auto alloc = [&](size_t bytes) {
        void* p = ws + off;
        off += (bytes + 255) & ~(size_t)255;
        return p;
    };
    int*   ei32      = (int*)  alloc((size_t)2 * NEDGE * 4);
    int*   cnt       = (int*)  alloc((size_t)N_NODES * 4);
    float* dinv      = (float*)alloc((size_t)N_NODES * 4);
    int*   row_start = (int*)  alloc((size_t)(N_NODES + 1) * 4);
    int*   pos       = (int*)  alloc((size_t)N_NODES * 4);
    int*   csr       = (int*)  alloc((size_t)NEDGE * 4);
    int*   bsum      = (int*)  alloc((size_t)NBLK * 4);
    int*   boff      = (int*)  alloc((size_t)NBLK * 4);
    unsigned short* h  = (unsigned short*)alloc((size_t)N_NODES * ODIM2 * 2);
    unsigned short* Wp = (unsigned short*)alloc((size_t)65536 * 2);

    hipMemsetAsync(cnt, 0, N_NODES * sizeof(int), stream);

    k_conv_count<<<(NEDGE + 255) / 256, 256, 0, stream>>>(ei, ei32, cnt);
    k_blocksum  <<<NBLK,                256, 0, stream>>>(cnt, bsum);
    k_scanblocks<<<1,                   256, 0, stream>>>(bsum, boff);
    k_apply     <<<NBLK,                256, 0, stream>>>(cnt, boff, row_start, pos, dinv);
    k_fill      <<<(NEDGE + 255) / 256, 256, 0, stream>>>(ei32, pos, csr);
    k_wconv     <<<32,                  256, 0, stream>>>(Wmu, Wls, Wp);
    k_gemm_mfma <<<(N_NODES + 63) / 64, 256, 0, stream>>>(x, Wp, h);
    k_gather    <<<N_NODES / 4,         256, 0, stream>>>(row_start, csr, dinv, h,
                                                          eps, bmu, bls, z);
}